// Round 13
// baseline (1841.007 us; speedup 1.0000x reference)
//
#include <hip/hip_runtime.h>
#include <cstdint>
#include <cstddef>

// Problem constants
#define B_    16
#define T_    32
#define H_    512
#define P_    1024        // 32*32 spatial
#define NPOS  16384       // B_*P_
#define NG    2048        // 4*H_

typedef __attribute__((ext_vector_type(8))) short short8;
typedef __attribute__((ext_vector_type(4))) float f32x4;

__device__ __forceinline__ unsigned short f2bf(float f) {
  uint32_t u = __float_as_uint(f);
  u += 0x7fffu + ((u >> 16) & 1u);     // RNE
  return (unsigned short)(u >> 16);
}
__device__ __forceinline__ float bflo(uint32_t u) { return __uint_as_float(u << 16); }
__device__ __forceinline__ float bfhi(uint32_t u) { return __uint_as_float(u & 0xffff0000u); }

__device__ __forceinline__ float sigf(float x) {
  return __builtin_amdgcn_rcpf(1.0f + __expf(-x));
}
__device__ __forceinline__ float tanhf_(float x) {
  return 1.0f - 2.0f * __builtin_amdgcn_rcpf(__expf(2.0f * x) + 1.0f);
}

__device__ __forceinline__ void gload_lds16(const void* g, void* l) {
  __builtin_amdgcn_global_load_lds(
      (const __attribute__((address_space(1))) void*)g,
      (__attribute__((address_space(3))) void*)l, 16, 0, 0);
}

// ---------------- repack kernels ----------------
// Wp[r][k] = bf16(Wc[o][1+k]),  r = ch*4+g,  o = g*512+ch  (k-contiguous rows)
__global__ void repack_w(const float* __restrict__ Wc, const float* __restrict__ bconv,
                         unsigned short* __restrict__ Wp, float* __restrict__ w0x,
                         float* __restrict__ bx) {
  int idx = blockIdx.x * 256 + threadIdx.x;       // 2048*512 exact
  int r = idx >> 9, k = idx & 511;
  int ch = r >> 2, g = r & 3;
  int o = g * 512 + ch;
  Wp[idx] = f2bf(Wc[o * 513 + 1 + k]);
  if (k == 0) { w0x[r] = Wc[o * 513]; bx[r] = bconv[o]; }
}

// wppb: split-bf16 W_post table for the fused u-GEMM.
// wppb[0][j][c] = bf16_hi(W_post[0][c][j]), wppb[1][j][c] = bf16(val - hi).
// j in [0,16) rows (j>=9 zero-padded) so j can sit on the MFMA A-row = lane.
__global__ void repack_wpost(const float* __restrict__ Wpost, unsigned short* __restrict__ wppb) {
  int idx = blockIdx.x * 256 + threadIdx.x;       // 16*512 = 8192 exact
  if (idx >= 16 * 512) return;
  int j = idx >> 9, c = idx & 511;
  float v = (j < 9) ? Wpost[c * 9 + j] : 0.f;
  unsigned short hi = f2bf(v);
  float lo = v - bflo((uint32_t)hi);
  wppb[idx] = hi;
  wppb[16 * 512 + idx] = f2bf(lo);
}

// ---------------- fused gates-GEMM + LSTM pointwise + u-GEMM + stencil ----------------
// R12-verified core (52.0 us): 256x128 tile, 4 waves, 48 KB single-buffer,
// 2-barrier K-loop, T1 XCD swizzle (FETCH 76->33 MB), stash XOR-swizzle
// (conflicts 4.1M->327K), phase-2 u-GEMM on the stash (8 MFMAs, split-bf16 wpp,
// verified free). NEW vs R12: the 3x3 stencil for step t-1 is fused into the
// prologue (16 threads, overlapped with chunk-0 staging latency -- the exact
// R6-verified-free pattern), enabled by DOUBLE-BUFFERED up: stencil reads
// up[(t-1)&1], phase-2 writes up[t&1] -- disjoint, no cross-block race.
// Deletes 32 conv_st2 launches (~80 us of launch-dominated dispatches).
// K-loop is rotated (stage kc+1 after the reads-done barrier) so op order is
// identical to R12's verified loop.
__global__ __launch_bounds__(256, 2)
void lstm_step(const unsigned short* __restrict__ Wp,
               const unsigned short* __restrict__ hprev,
               unsigned short* __restrict__ hnext,
               _Float16* __restrict__ Cst,
               const float* __restrict__ w0x, const float* __restrict__ bxv,
               const float* __restrict__ xin,
               const unsigned short* __restrict__ wppb,
               const float* __restrict__ upPrev, float* __restrict__ upCur,
               const float* __restrict__ bpost, float* __restrict__ out, int t) {
  __shared__ unsigned short As[256 * 64];   // W tile   [row r][k], XOR-swizzled chunks (32 KB)
  __shared__ unsigned short Bs[128 * 64];   // h tile   [pos][k],   XOR-swizzled chunks (16 KB)

  const int tid = threadIdx.x;
  const int lane = tid & 63;
  const int wv = tid >> 6;
  const int wm = wv >> 1, wn = wv & 1;      // 2x2 waves over 256x128 tile
  const int q = lane >> 4, l = lane & 15;

  // T1 XCD swizzle: each XCD owns 16 contiguous pos-tiles x all 8 row-tiles.
  const int lid = blockIdx.x;               // 0..1023
  const int xcd = lid & 7;
  const int s   = lid >> 3;                 // 0..127
  const int ny  = xcd * 16 + (s & 15);      // pos-tile 0..127
  const int rx  = s >> 4;                   // row-tile 0..7
  const int r0  = rx * 256;                 // gate-row base
  const int n0  = ny * 128;                 // position base
  const int ch0 = rx * 64;

  // staging map: lds byte j*4096 + tid*16 -> row j*32 + (tid>>3), stored chunk tid&7
  const int srow = tid >> 3;
  const int lchunk = (tid & 7) ^ (srow & 7);
  const unsigned short* gA = Wp    + (size_t)(r0 + srow) * 512 + lchunk * 8;
  const unsigned short* gB = hprev + (size_t)(n0 + srow) * 512 + lchunk * 8;
  char* lA = (char*)As + wv * 1024;
  char* lB = (char*)Bs + wv * 1024;

  f32x4 acc[8][4] = {};

  // issue chunk-0 staging first, then overlap the fused stencil with its latency
#pragma unroll
  for (int j = 0; j < 8; ++j)
    gload_lds16(gA + (size_t)j * (32 * 512), lA + j * 4096);
#pragma unroll
  for (int j = 0; j < 4; ++j)
    gload_lds16(gB + (size_t)j * (32 * 512), lB + j * 4096);

  // fused 3x3 stencil for step t-1 (R6-verified-free placement)
  if (t > 0 && tid < 16) {
    int pix = lid * 16 + tid;               // 1024*16 = 16384 exact
    int b = pix >> 10, p = pix & 1023;
    int py = p >> 5, px = p & 31;
    float a = bpost[0];
#pragma unroll
    for (int dy = -1; dy <= 1; ++dy) {
      int nyy = py + dy;
      if ((unsigned)nyy > 31u) continue;
#pragma unroll
      for (int dx = -1; dx <= 1; ++dx) {
        int nx = px + dx;
        if ((unsigned)nx > 31u) continue;
        int j = (dy + 1) * 3 + (dx + 1);
        int np = (b << 10) + (nyy << 5) + nx;
#pragma unroll
        for (int rr = 0; rr < 8; ++rr)
          a += upPrev[(size_t)(rr * 9 + j) * NPOS + np];
      }
    }
    out[((b * T_ + (t - 1)) << 10) + p] = a;
  }

  for (int kc = 0; kc < 512; kc += 64) {
    __syncthreads();                        // implicit vmcnt drain: chunk kc ready

#pragma unroll
    for (int kk = 0; kk < 2; ++kk) {
      short8 af[8], bf_[4];
#pragma unroll
      for (int mi = 0; mi < 8; ++mi) {
        int row = wm * 128 + mi * 16 + l;
        int sidx = row * 64 + (((kk * 4 + q) ^ (row & 7)) * 8);
        af[mi] = *(const short8*)(As + sidx);
      }
#pragma unroll
      for (int ni = 0; ni < 4; ++ni) {
        int row = wn * 64 + ni * 16 + l;
        int sidx = row * 64 + (((kk * 4 + q) ^ (row & 7)) * 8);
        bf_[ni] = *(const short8*)(Bs + sidx);
      }
#pragma unroll
      for (int mi = 0; mi < 8; ++mi)
#pragma unroll
        for (int ni = 0; ni < 4; ++ni)
          acc[mi][ni] = __builtin_amdgcn_mfma_f32_16x16x32_bf16(af[mi], bf_[ni], acc[mi][ni], 0, 0, 0);
    }
    __syncthreads();                        // reads done -> safe to overwrite

    if (kc < 448) {
      int kn = kc + 64;
#pragma unroll
      for (int j = 0; j < 8; ++j)
        gload_lds16(gA + (size_t)j * (32 * 512) + kn, lA + j * 4096);
#pragma unroll
      for (int j = 0; j < 4; ++j)
        gload_lds16(gB + (size_t)j * (32 * 512) + kn, lB + j * 4096);
    }
  }

  // ---- epilogue: lane's 4 regs of acc[mi][ni] = (i,f,o,g) for one (ch,pos) ----
  float xv[4]; int posL[4]; size_t cbase[4];
#pragma unroll
  for (int ni = 0; ni < 4; ++ni) {
    posL[ni] = wn * 64 + ni * 16 + l;
    int pos = n0 + posL[ni];
    int b = pos >> 10, p = pos & 1023;
    xv[ni] = xin[((b * T_ + t) << 10) + p];
    cbase[ni] = ((size_t)b << 19) + p;    // b*512*1024 + p
  }
#pragma unroll
  for (int mi = 0; mi < 8; ++mi) {
    int chl = wm * 32 + mi * 4 + q;                    // local ch 0..63
    int rg = r0 + wm * 128 + mi * 16 + q * 4;          // global row of reg0
    float4 w0 = *(const float4*)(w0x + rg);
    float4 bb = *(const float4*)(bxv + rg);
    int ch = ch0 + chl;
#pragma unroll
    for (int ni = 0; ni < 4; ++ni) {
      f32x4 g = acc[mi][ni];
      float gi = g[0] + w0.x * xv[ni] + bb.x;
      float gf = g[1] + w0.y * xv[ni] + bb.y;
      float go = g[2] + w0.z * xv[ni] + bb.z;
      float gg = g[3] + w0.w * xv[ni] + bb.w;
      size_t cidx = cbase[ni] + ((size_t)ch << 10);
      float cold = (float)Cst[cidx];
      float cn = sigf(gf) * cold + sigf(gi) + tanhf_(gg);
      float hn = sigf(go) + tanhf_(cn);
      Cst[cidx] = (_Float16)cn;
      // stash for coalesced store, chunk-XOR swizzled (verified 327K conflicts)
      As[posL[ni] * 64 + (chl ^ ((posL[ni] & 7) << 3))] = f2bf(hn);
    }
  }
  __syncthreads();

  // h store (reads stash)
  {
    int pl = tid >> 1;                 // 0..127 local pos
    int cb2 = (tid & 1) << 2;          // chunk base: 0 or 4 (8-short chunks)
    const unsigned short* srcrow = As + pl * 64;
    unsigned short* dst = hnext + (size_t)(n0 + pl) * 512 + ch0 + (cb2 << 3);
#pragma unroll
    for (int i = 0; i < 4; ++i)
      ((uint4*)dst)[i] = *(const uint4*)(srcrow + (((cb2 + i) ^ (pl & 7)) << 3));
  }

  // ---- phase-2: upCur[rx][j][pix] = sum_{ch in block} wpp[j][ch] * h[pos][ch] ----
  // 16x128x64 GEMM on the stash: A = wppb rows (j = lane&15, zero-padded to 16),
  // B = stash rows (pos). 2 k-chunks x 2 pos-groups x {hi,lo} = 8 MFMAs/wave.
  {
    const unsigned short* wb_hi = wppb;               // [16][512]
    const unsigned short* wb_lo = wppb + 16 * 512;
    const int posg = wv * 32;                         // wave's 32 positions
    f32x4 a2[2] = {};
#pragma unroll
    for (int kk = 0; kk < 2; ++kk) {
      const int wo = l * 512 + ch0 + kk * 32 + q * 8;
      short8 whi = *(const short8*)(wb_hi + wo);
      short8 wlo = *(const short8*)(wb_lo + wo);
#pragma unroll
      for (int ni2 = 0; ni2 < 2; ++ni2) {
        int row = posg + ni2 * 16 + l;
        int sidx = row * 64 + (((kk * 4 + q) ^ (row & 7)) * 8);
        short8 hf = *(const short8*)(As + sidx);
        a2[ni2] = __builtin_amdgcn_mfma_f32_16x16x32_bf16(whi, hf, a2[ni2], 0, 0, 0);
        a2[ni2] = __builtin_amdgcn_mfma_f32_16x16x32_bf16(wlo, hf, a2[ni2], 0, 0, 0);
      }
    }
#pragma unroll
    for (int ni2 = 0; ni2 < 2; ++ni2) {
      int pix = n0 + posg + ni2 * 16 + l;
#pragma unroll
      for (int r = 0; r < 4; ++r) {
        int j = q * 4 + r;
        if (j < 9)
          upCur[(size_t)(rx * 9 + j) * NPOS + pix] = a2[ni2][r];
      }
    }
  }
}

// ---------------- 3x3 stencil over the 8 rx-partials (tail, t=T-1 only) ----------------
__global__ __launch_bounds__(256)
void conv_st2(const float* __restrict__ up, const float* __restrict__ bpost,
              float* __restrict__ out, int t) {
  int idx = blockIdx.x * 256 + threadIdx.x;        // 0..16383
  int b = idx >> 10, p = idx & 1023;
  int py = p >> 5, px = p & 31;
  float acc = bpost[0];
#pragma unroll
  for (int dy = -1; dy <= 1; ++dy) {
    int ny = py + dy;
    if ((unsigned)ny > 31u) continue;
#pragma unroll
    for (int dx = -1; dx <= 1; ++dx) {
      int nx = px + dx;
      if ((unsigned)nx > 31u) continue;
      int j = (dy + 1) * 3 + (dx + 1);
      int np = (b << 10) + (ny << 5) + nx;
#pragma unroll
      for (int rxx = 0; rxx < 8; ++rxx)
        acc += up[(size_t)(rxx * 9 + j) * NPOS + np];
    }
  }
  out[((b * T_ + t) << 10) + p] = acc;
}

// ---------------- launch ----------------
extern "C" void kernel_launch(void* const* d_in, const int* in_sizes, int n_in,
                              void* d_out, int out_size, void* d_ws, size_t ws_size,
                              hipStream_t stream) {
  const float* x     = (const float*)d_in[0];
  const float* Wconv = (const float*)d_in[1];
  const float* bconv = (const float*)d_in[2];
  const float* Wpost = (const float*)d_in[3];
  const float* bpost = (const float*)d_in[4];
  float* out = (float*)d_out;
  char* ws = (char*)d_ws;

  // workspace layout (bytes)
  unsigned short* h0   = (unsigned short*)(ws);                 // 16 MB
  unsigned short* h1   = (unsigned short*)(ws + 16777216);      // 16 MB
  _Float16*       Cst  = (_Float16*)(ws + 33554432);            // 16 MB (fp16 state)
  unsigned short* Wp   = (unsigned short*)(ws + 50331648);      // 2 MB
  float*          w0x  = (float*)(ws + 52428800);               // 8 KB
  float*          bx   = (float*)(ws + 52436992);               // 8 KB
  unsigned short* wppb = (unsigned short*)(ws + 52445184);      // 32 KB (split-bf16 W_post)
  float*          up0  = (float*)(ws + 52477952);               // 4.72 MB (8*9*16384 f32)
  float*          up1  = (float*)(ws + 57196544);               // 4.72 MB

  hipMemsetAsync(h0, 0, 16777216, stream);
  hipMemsetAsync(Cst, 0, 16777216, stream);
  repack_w<<<4096, 256, 0, stream>>>(Wconv, bconv, Wp, w0x, bx);
  repack_wpost<<<32, 256, 0, stream>>>(Wpost, wppb);

  unsigned short* hp = h0;
  unsigned short* hn = h1;
  for (int t = 0; t < T_; ++t) {
    const float* upPrev = (t & 1) ? up0 : up1;   // written by step t-1
    float*       upCur  = (t & 1) ? up1 : up0;
    lstm_step<<<1024, 256, 0, stream>>>(Wp, hp, hn, Cst, w0x, bx, x, wppb,
                                        upPrev, upCur, bpost, out, t);
    unsigned short* tmp = hp; hp = hn; hn = tmp;
  }
  conv_st2<<<64, 256, 0, stream>>>((T_ & 1) ? up0 : up1, bpost, out, T_ - 1);
}

// Round 14
// 1761.471 us; speedup vs baseline: 1.0452x; 1.0452x over previous
//
#include <hip/hip_runtime.h>
#include <cstdint>
#include <cstddef>

// Problem constants
#define B_    16
#define T_    32
#define H_    512
#define P_    1024        // 32*32 spatial
#define NPOS  16384       // B_*P_
#define NG    2048        // 4*H_

typedef __attribute__((ext_vector_type(8))) short short8;
typedef __attribute__((ext_vector_type(4))) float f32x4;

__device__ __forceinline__ unsigned short f2bf(float f) {
  uint32_t u = __float_as_uint(f);
  u += 0x7fffu + ((u >> 16) & 1u);     // RNE
  return (unsigned short)(u >> 16);
}
__device__ __forceinline__ float bflo(uint32_t u) { return __uint_as_float(u << 16); }
__device__ __forceinline__ float bfhi(uint32_t u) { return __uint_as_float(u & 0xffff0000u); }

__device__ __forceinline__ float sigf(float x) {
  return __builtin_amdgcn_rcpf(1.0f + __expf(-x));
}
__device__ __forceinline__ float tanhf_(float x) {
  return 1.0f - 2.0f * __builtin_amdgcn_rcpf(__expf(2.0f * x) + 1.0f);
}

__device__ __forceinline__ void gload_lds16(const void* g, void* l) {
  __builtin_amdgcn_global_load_lds(
      (const __attribute__((address_space(1))) void*)g,
      (__attribute__((address_space(3))) void*)l, 16, 0, 0);
}

// ---------------- repack kernels ----------------
// Wp[r][k] = bf16(Wc[o][1+k]),  r = ch*4+g,  o = g*512+ch  (k-contiguous rows)
__global__ void repack_w(const float* __restrict__ Wc, const float* __restrict__ bconv,
                         unsigned short* __restrict__ Wp, float* __restrict__ w0x,
                         float* __restrict__ bx) {
  int idx = blockIdx.x * 256 + threadIdx.x;       // 2048*512 exact
  int r = idx >> 9, k = idx & 511;
  int ch = r >> 2, g = r & 3;
  int o = g * 512 + ch;
  Wp[idx] = f2bf(Wc[o * 513 + 1 + k]);
  if (k == 0) { w0x[r] = Wc[o * 513]; bx[r] = bconv[o]; }
}

// wppb: split-bf16 W_post table for the fused u-GEMM.
// wppb[0][j][c] = bf16_hi(W_post[0][c][j]), wppb[1][j][c] = bf16(val - hi).
// j in [0,16) rows (j>=9 zero-padded) so j can sit on the MFMA A-row = lane.
__global__ void repack_wpost(const float* __restrict__ Wpost, unsigned short* __restrict__ wppb) {
  int idx = blockIdx.x * 256 + threadIdx.x;       // 16*512 = 8192 exact
  if (idx >= 16 * 512) return;
  int j = idx >> 9, c = idx & 511;
  float v = (j < 9) ? Wpost[c * 9 + j] : 0.f;
  unsigned short hi = f2bf(v);
  float lo = v - bflo((uint32_t)hi);
  wppb[idx] = hi;
  wppb[16 * 512 + idx] = f2bf(lo);
}

// ---------------- fused gates-GEMM + LSTM pointwise + u-GEMM + stencil ----------------
// R12-verified core (52.0 us): 256x128 tile, 4 waves, 48 KB single-buffer,
// 2-barrier K-loop, T1 XCD swizzle (FETCH 76->33 MB), stash XOR-swizzle
// (conflicts 4.1M->327K), phase-2 u-GEMM on the stash (8 MFMAs, split-bf16,
// verified free in R12). R13's 72-load fused stencil cost 7.5 us/step -- fixed
// by reducing the 8 rx-partials AT THE PRODUCER: phase-2 accumulates into a
// single u[j][pix] (590 KB) via unsafeAtomicAdd (HW global_atomic_add_f32;
// all 8 rx-writers of a pixel are on the SAME XCD under the T1 swizzle, so
// atomics resolve in the local L2). The prologue stencil is back to R6's
// verified-free 9-load form. Triple-buffered u: step t accumulates u[t%3],
// stencil reads u[(t-1)%3], threads 16..159 zero u[(t+1)%3] (144 f32/block).
__global__ __launch_bounds__(256, 2)
void lstm_step(const unsigned short* __restrict__ Wp,
               const unsigned short* __restrict__ hprev,
               unsigned short* __restrict__ hnext,
               _Float16* __restrict__ Cst,
               const float* __restrict__ w0x, const float* __restrict__ bxv,
               const float* __restrict__ xin,
               const unsigned short* __restrict__ wppb,
               const float* __restrict__ uPrev, float* __restrict__ uCur,
               float* __restrict__ uNext,
               const float* __restrict__ bpost, float* __restrict__ out, int t) {
  __shared__ unsigned short As[256 * 64];   // W tile   [row r][k], XOR-swizzled chunks (32 KB)
  __shared__ unsigned short Bs[128 * 64];   // h tile   [pos][k],   XOR-swizzled chunks (16 KB)

  const int tid = threadIdx.x;
  const int lane = tid & 63;
  const int wv = tid >> 6;
  const int wm = wv >> 1, wn = wv & 1;      // 2x2 waves over 256x128 tile
  const int q = lane >> 4, l = lane & 15;

  // T1 XCD swizzle: each XCD owns 16 contiguous pos-tiles x all 8 row-tiles.
  const int lid = blockIdx.x;               // 0..1023
  const int xcd = lid & 7;
  const int s   = lid >> 3;                 // 0..127
  const int ny  = xcd * 16 + (s & 15);      // pos-tile 0..127
  const int rx  = s >> 4;                   // row-tile 0..7
  const int r0  = rx * 256;                 // gate-row base
  const int n0  = ny * 128;                 // position base
  const int ch0 = rx * 64;

  // staging map: lds byte j*4096 + tid*16 -> row j*32 + (tid>>3), stored chunk tid&7
  const int srow = tid >> 3;
  const int lchunk = (tid & 7) ^ (srow & 7);
  const unsigned short* gA = Wp    + (size_t)(r0 + srow) * 512 + lchunk * 8;
  const unsigned short* gB = hprev + (size_t)(n0 + srow) * 512 + lchunk * 8;
  char* lA = (char*)As + wv * 1024;
  char* lB = (char*)Bs + wv * 1024;

  f32x4 acc[8][4] = {};

  // issue chunk-0 staging first, then overlap stencil + u-zeroing with its latency
#pragma unroll
  for (int j = 0; j < 8; ++j)
    gload_lds16(gA + (size_t)j * (32 * 512), lA + j * 4096);
#pragma unroll
  for (int j = 0; j < 4; ++j)
    gload_lds16(gB + (size_t)j * (32 * 512), lB + j * 4096);

  // fused 3x3 stencil for step t-1 (R6-verified-free 9-load form)
  if (t > 0 && tid < 16) {
    int pix = lid * 16 + tid;               // 1024*16 = 16384 exact
    int b = pix >> 10, p = pix & 1023;
    int py = p >> 5, px = p & 31;
    float a = bpost[0];
#pragma unroll
    for (int dy = -1; dy <= 1; ++dy) {
      int nyy = py + dy;
      if ((unsigned)nyy > 31u) continue;
#pragma unroll
      for (int dx = -1; dx <= 1; ++dx) {
        int nx = px + dx;
        if ((unsigned)nx > 31u) continue;
        int j = (dy + 1) * 3 + (dx + 1);
        a += uPrev[j * NPOS + (b << 10) + (nyy << 5) + nx];
      }
    }
    out[((b * T_ + (t - 1)) << 10) + p] = a;
  }
  // zero u[(t+1)%3] for the NEXT step's accumulation (9*NPOS = 147456 = 1024*144)
  if (tid >= 16 && tid < 160)
    uNext[lid * 144 + (tid - 16)] = 0.f;

  for (int kc = 0; kc < 512; kc += 64) {
    __syncthreads();                        // implicit vmcnt drain: chunk kc ready

#pragma unroll
    for (int kk = 0; kk < 2; ++kk) {
      short8 af[8], bf_[4];
#pragma unroll
      for (int mi = 0; mi < 8; ++mi) {
        int row = wm * 128 + mi * 16 + l;
        int sidx = row * 64 + (((kk * 4 + q) ^ (row & 7)) * 8);
        af[mi] = *(const short8*)(As + sidx);
      }
#pragma unroll
      for (int ni = 0; ni < 4; ++ni) {
        int row = wn * 64 + ni * 16 + l;
        int sidx = row * 64 + (((kk * 4 + q) ^ (row & 7)) * 8);
        bf_[ni] = *(const short8*)(Bs + sidx);
      }
#pragma unroll
      for (int mi = 0; mi < 8; ++mi)
#pragma unroll
        for (int ni = 0; ni < 4; ++ni)
          acc[mi][ni] = __builtin_amdgcn_mfma_f32_16x16x32_bf16(af[mi], bf_[ni], acc[mi][ni], 0, 0, 0);
    }
    __syncthreads();                        // reads done -> safe to overwrite

    if (kc < 448) {
      int kn = kc + 64;
#pragma unroll
      for (int j = 0; j < 8; ++j)
        gload_lds16(gA + (size_t)j * (32 * 512) + kn, lA + j * 4096);
#pragma unroll
      for (int j = 0; j < 4; ++j)
        gload_lds16(gB + (size_t)j * (32 * 512) + kn, lB + j * 4096);
    }
  }

  // ---- epilogue: lane's 4 regs of acc[mi][ni] = (i,f,o,g) for one (ch,pos) ----
  float xv[4]; int posL[4]; size_t cbase[4];
#pragma unroll
  for (int ni = 0; ni < 4; ++ni) {
    posL[ni] = wn * 64 + ni * 16 + l;
    int pos = n0 + posL[ni];
    int b = pos >> 10, p = pos & 1023;
    xv[ni] = xin[((b * T_ + t) << 10) + p];
    cbase[ni] = ((size_t)b << 19) + p;    // b*512*1024 + p
  }
#pragma unroll
  for (int mi = 0; mi < 8; ++mi) {
    int chl = wm * 32 + mi * 4 + q;                    // local ch 0..63
    int rg = r0 + wm * 128 + mi * 16 + q * 4;          // global row of reg0
    float4 w0 = *(const float4*)(w0x + rg);
    float4 bb = *(const float4*)(bxv + rg);
    int ch = ch0 + chl;
#pragma unroll
    for (int ni = 0; ni < 4; ++ni) {
      f32x4 g = acc[mi][ni];
      float gi = g[0] + w0.x * xv[ni] + bb.x;
      float gf = g[1] + w0.y * xv[ni] + bb.y;
      float go = g[2] + w0.z * xv[ni] + bb.z;
      float gg = g[3] + w0.w * xv[ni] + bb.w;
      size_t cidx = cbase[ni] + ((size_t)ch << 10);
      float cold = (float)Cst[cidx];
      float cn = sigf(gf) * cold + sigf(gi) + tanhf_(gg);
      float hn = sigf(go) + tanhf_(cn);
      Cst[cidx] = (_Float16)cn;
      // stash for coalesced store, chunk-XOR swizzled (verified 327K conflicts)
      As[posL[ni] * 64 + (chl ^ ((posL[ni] & 7) << 3))] = f2bf(hn);
    }
  }
  __syncthreads();

  // h store (reads stash)
  {
    int pl = tid >> 1;                 // 0..127 local pos
    int cb2 = (tid & 1) << 2;          // chunk base: 0 or 4 (8-short chunks)
    const unsigned short* srcrow = As + pl * 64;
    unsigned short* dst = hnext + (size_t)(n0 + pl) * 512 + ch0 + (cb2 << 3);
#pragma unroll
    for (int i = 0; i < 4; ++i)
      ((uint4*)dst)[i] = *(const uint4*)(srcrow + (((cb2 + i) ^ (pl & 7)) << 3));
  }

  // ---- phase-2: uCur[j][pix] += sum_{ch in block} wpp[j][ch] * h[pos][ch] ----
  // 16x128x64 GEMM on the stash (8 MFMAs, split-bf16). The 8 rx-blocks of a
  // pixel accumulate via HW f32 atomicAdd -- same-XCD, L2-resident.
  {
    const unsigned short* wb_hi = wppb;               // [16][512]
    const unsigned short* wb_lo = wppb + 16 * 512;
    const int posg = wv * 32;                         // wave's 32 positions
    f32x4 a2[2] = {};
#pragma unroll
    for (int kk = 0; kk < 2; ++kk) {
      const int wo = l * 512 + ch0 + kk * 32 + q * 8;
      short8 whi = *(const short8*)(wb_hi + wo);
      short8 wlo = *(const short8*)(wb_lo + wo);
#pragma unroll
      for (int ni2 = 0; ni2 < 2; ++ni2) {
        int row = posg + ni2 * 16 + l;
        int sidx = row * 64 + (((kk * 4 + q) ^ (row & 7)) * 8);
        short8 hf = *(const short8*)(As + sidx);
        a2[ni2] = __builtin_amdgcn_mfma_f32_16x16x32_bf16(whi, hf, a2[ni2], 0, 0, 0);
        a2[ni2] = __builtin_amdgcn_mfma_f32_16x16x32_bf16(wlo, hf, a2[ni2], 0, 0, 0);
      }
    }
#pragma unroll
    for (int ni2 = 0; ni2 < 2; ++ni2) {
      int pix = n0 + posg + ni2 * 16 + l;
#pragma unroll
      for (int r = 0; r < 4; ++r) {
        int j = q * 4 + r;
        if (j < 9)
          unsafeAtomicAdd(&uCur[j * NPOS + pix], a2[ni2][r]);
      }
    }
  }
}

// ---------------- 3x3 stencil over u (tail, t=T-1 only) ----------------
__global__ __launch_bounds__(256)
void conv_st(const float* __restrict__ u, const float* __restrict__ bpost,
             float* __restrict__ out, int t) {
  int idx = blockIdx.x * 256 + threadIdx.x;        // 0..16383
  int b = idx >> 10, p = idx & 1023;
  int py = p >> 5, px = p & 31;
  float acc = bpost[0];
#pragma unroll
  for (int dy = -1; dy <= 1; ++dy) {
    int ny = py + dy;
    if ((unsigned)ny > 31u) continue;
#pragma unroll
    for (int dx = -1; dx <= 1; ++dx) {
      int nx = px + dx;
      if ((unsigned)nx > 31u) continue;
      int j = (dy + 1) * 3 + (dx + 1);
      acc += u[j * NPOS + (b << 10) + (ny << 5) + nx];
    }
  }
  out[((b * T_ + t) << 10) + p] = acc;
}

// ---------------- launch ----------------
extern "C" void kernel_launch(void* const* d_in, const int* in_sizes, int n_in,
                              void* d_out, int out_size, void* d_ws, size_t ws_size,
                              hipStream_t stream) {
  const float* x     = (const float*)d_in[0];
  const float* Wconv = (const float*)d_in[1];
  const float* bconv = (const float*)d_in[2];
  const float* Wpost = (const float*)d_in[3];
  const float* bpost = (const float*)d_in[4];
  float* out = (float*)d_out;
  char* ws = (char*)d_ws;

  // workspace layout (bytes)
  unsigned short* h0   = (unsigned short*)(ws);                 // 16 MB
  unsigned short* h1   = (unsigned short*)(ws + 16777216);      // 16 MB
  _Float16*       Cst  = (_Float16*)(ws + 33554432);            // 16 MB (fp16 state)
  unsigned short* Wp   = (unsigned short*)(ws + 50331648);      // 2 MB
  float*          w0x  = (float*)(ws + 52428800);               // 8 KB
  float*          bx   = (float*)(ws + 52436992);               // 8 KB
  unsigned short* wppb = (unsigned short*)(ws + 52445184);      // 32 KB (split-bf16 W_post)
  float*          u0   = (float*)(ws + 52477952);               // 576 KB (9*16384 f32)
  float*          u1   = (float*)(ws + 53067776);               // 576 KB
  float*          u2   = (float*)(ws + 53657600);               // 576 KB
  float* ub[3] = {u0, u1, u2};

  hipMemsetAsync(h0, 0, 16777216, stream);
  hipMemsetAsync(Cst, 0, 16777216, stream);
  hipMemsetAsync(u0, 0, 589824, stream);
  repack_w<<<4096, 256, 0, stream>>>(Wconv, bconv, Wp, w0x, bx);
  repack_wpost<<<32, 256, 0, stream>>>(Wpost, wppb);

  unsigned short* hp = h0;
  unsigned short* hn = h1;
  for (int t = 0; t < T_; ++t) {
    const float* uPrev = ub[(t + 2) % 3];   // written by step t-1
    float*       uCur  = ub[t % 3];         // accumulated this step (pre-zeroed)
    float*       uNext = ub[(t + 1) % 3];   // zeroed this step for step t+1
    lstm_step<<<1024, 256, 0, stream>>>(Wp, hp, hn, Cst, w0x, bx, x, wppb,
                                        uPrev, uCur, uNext, bpost, out, t);
    unsigned short* tmp = hp; hp = hn; hn = tmp;
  }
  conv_st<<<64, 256, 0, stream>>>(ub[(T_ - 1) % 3], bpost, out, T_ - 1);
}